// Round 2
// baseline (1132.803 us; speedup 1.0000x reference)
//
#include <hip/hip_runtime.h>

typedef unsigned short u16;
typedef unsigned int u32;

__device__ __forceinline__ float b2f(u16 u) {
    union { unsigned int i; float f; } v;
    v.i = ((unsigned int)u) << 16;
    return v.f;
}
__device__ __forceinline__ u16 f2b(float f) {
    union { float ff; unsigned int i; } v;
    v.ff = f;
    unsigned int x = v.i;
    return (u16)((x + 0x7fffu + ((x >> 16) & 1u)) >> 16);
}

// dtype flag: cos[0] row is all 1.0. fp32 -> first u32 = 0x3F800000,
// bf16 -> first u32 = 0x3F803F80 (two packed bf16 ones).
__device__ __forceinline__ bool detect_bf16(const void* cosT) {
    return ((*(const u32*)cosT) & 0xffffu) == 0x3f80u;
}

// load 4 consecutive elements (element offset `off`, multiple of 4) as fp32
__device__ __forceinline__ float4 ld4(const void* p, size_t off, bool isbf) {
    if (isbf) {
        ushort4 v = *(const ushort4*)((const u16*)p + off);
        return make_float4(b2f(v.x), b2f(v.y), b2f(v.z), b2f(v.w));
    }
    return *(const float4*)((const float*)p + off);
}

// softcap + sliding-window mask. SCALING = 1/16, SOFTCAP = 50.
__device__ __forceinline__ float capmask(float sdot, int i, int j) {
    float v = sdot * (0.0625f / 50.0f);
    v = fminf(fmaxf(v, -10.0f), 10.0f);
    float e = __expf(2.0f * v);
    float c = 50.0f * (e - 1.0f) / (e + 1.0f);
    bool allowed = (j <= i) && (j > i - 512);
    return allowed ? c : -1e30f;
}

// ---------------------------------------------------------------------------
// Kernel 1: QKV projection GEMM.  C[8192 x 1536] = hidden[8192 x 640] @ [Wq|Wk|Wv]
// BM=128 BN=128 BK=8, 256 threads, 8x8 micro-tile, fp32 accumulate.
// Inputs dual-dtype; outputs canonical bf16 workspace.
// ---------------------------------------------------------------------------
__global__ __launch_bounds__(256) void qkv_gemm(
    const void* __restrict__ hidden,
    const void* __restrict__ Wq,
    const void* __restrict__ Wk,
    const void* __restrict__ Wv,
    const void* __restrict__ cosT,
    u16* __restrict__ Qb,   // [8192][1024]
    u16* __restrict__ Kb,   // [8192][256]
    u16* __restrict__ Vb)   // [8192][256]
{
    const bool isbf = detect_bf16(cosT);
    const int n0 = blockIdx.x * 128;
    const int m0 = blockIdx.y * 128;
    const int t  = threadIdx.x;

    __shared__ float As[8][128];   // A transposed: As[k][m]
    __shared__ float Bs[8][128];

    const void* W; int ldw, coff, region;
    if (n0 < 1024)      { W = Wq; ldw = 1024; coff = n0;        region = 0; }
    else if (n0 < 1280) { W = Wk; ldw = 256;  coff = n0 - 1024; region = 1; }
    else                { W = Wv; ldw = 256;  coff = n0 - 1280; region = 2; }

    const int tm = t >> 4, tn = t & 15;
    const int a_m = t >> 1;
    const int a_k = (t & 1) * 4;
    const int b_k = t >> 5;
    const int b_n = (t & 31) * 4;

    float acc[8][8];
#pragma unroll
    for (int i = 0; i < 8; i++)
#pragma unroll
        for (int j = 0; j < 8; j++) acc[i][j] = 0.0f;

    const size_t a_off = (size_t)(m0 + a_m) * 640 + a_k;
    const size_t b_off = (size_t)b_k * ldw + coff + b_n;

    for (int kb = 0; kb < 640; kb += 8) {
        float4 av = ld4(hidden, a_off + kb, isbf);
        float4 bv = ld4(W, b_off + (size_t)kb * ldw, isbf);
        As[a_k + 0][a_m] = av.x;
        As[a_k + 1][a_m] = av.y;
        As[a_k + 2][a_m] = av.z;
        As[a_k + 3][a_m] = av.w;
        *(float4*)&Bs[b_k][b_n] = bv;
        __syncthreads();
#pragma unroll
        for (int kk = 0; kk < 8; kk++) {
            float a[8], b[8];
            *(float4*)&a[0] = *(const float4*)&As[kk][tm * 8];
            *(float4*)&a[4] = *(const float4*)&As[kk][tm * 8 + 4];
            *(float4*)&b[0] = *(const float4*)&Bs[kk][tn * 8];
            *(float4*)&b[4] = *(const float4*)&Bs[kk][tn * 8 + 4];
#pragma unroll
            for (int i = 0; i < 8; i++)
#pragma unroll
                for (int j = 0; j < 8; j++)
                    acc[i][j] += a[i] * b[j];
        }
        __syncthreads();
    }

    u16* dbase; int ldo;
    if (region == 0)      { dbase = Qb; ldo = 1024; }
    else if (region == 1) { dbase = Kb; ldo = 256; }
    else                  { dbase = Vb; ldo = 256; }

#pragma unroll
    for (int i = 0; i < 8; i++) {
        int row = m0 + tm * 8 + i;
        u16* p = dbase + (size_t)row * ldo + coff + tn * 8;
        *(ushort4*)p       = make_ushort4(f2b(acc[i][0]), f2b(acc[i][1]),
                                          f2b(acc[i][2]), f2b(acc[i][3]));
        *(ushort4*)(p + 4) = make_ushort4(f2b(acc[i][4]), f2b(acc[i][5]),
                                          f2b(acc[i][6]), f2b(acc[i][7]));
    }
}

// ---------------------------------------------------------------------------
// Kernel 2: fused RMS-norm + RoPE, in place on Qb (4 heads) and Kb (1 head).
// 320 threads = 5 waves; wave g in [0,3] -> q head g, wave 4 -> k.
// Lane holds 4 contiguous dims; rotate_half partner is lane^32 (d +/- 128).
// ---------------------------------------------------------------------------
__global__ __launch_bounds__(320) void norm_rope(
    u16* __restrict__ Qb, u16* __restrict__ Kb,
    const void* __restrict__ cosT, const void* __restrict__ sinT,
    const void* __restrict__ qw, const void* __restrict__ kw)
{
    const bool isbf = detect_bf16(cosT);
    const int row  = blockIdx.x;        // b*4096 + s
    const int s    = row & 4095;
    const int g    = threadIdx.x >> 6;
    const int lane = threadIdx.x & 63;
    const int d0   = lane * 4;

    u16* p;
    const void* w;
    if (g < 4) { p = Qb + (size_t)row * 1024 + g * 256 + d0; w = qw; }
    else       { p = Kb + (size_t)row * 256 + d0;            w = kw; }

    ushort4 xv = *(const ushort4*)p;
    float x0 = b2f(xv.x), x1 = b2f(xv.y), x2 = b2f(xv.z), x3 = b2f(xv.w);
    float ssum = x0 * x0 + x1 * x1 + x2 * x2 + x3 * x3;
#pragma unroll
    for (int off = 32; off > 0; off >>= 1) ssum += __shfl_xor(ssum, off, 64);
    float rs = rsqrtf(ssum * (1.0f / 256.0f) + 1e-6f);

    float4 wv = ld4(w, d0, isbf);
    float n0 = x0 * rs * (1.0f + wv.x);
    float n1 = x1 * rs * (1.0f + wv.y);
    float n2 = x2 * rs * (1.0f + wv.z);
    float n3 = x3 * rs * (1.0f + wv.w);

    float o0 = __shfl_xor(n0, 32, 64);
    float o1 = __shfl_xor(n1, 32, 64);
    float o2 = __shfl_xor(n2, 32, 64);
    float o3 = __shfl_xor(n3, 32, 64);
    float sgn = (lane < 32) ? -1.0f : 1.0f;

    float4 cv = ld4(cosT, (size_t)s * 256 + d0, isbf);
    float4 sv = ld4(sinT, (size_t)s * 256 + d0, isbf);
    float r0 = n0 * cv.x + sgn * o0 * sv.x;
    float r1 = n1 * cv.y + sgn * o1 * sv.y;
    float r2 = n2 * cv.z + sgn * o2 * sv.z;
    float r3 = n3 * cv.w + sgn * o3 * sv.w;
    *(ushort4*)p = make_ushort4(f2b(r0), f2b(r1), f2b(r2), f2b(r3));
}

// ---------------------------------------------------------------------------
// Kernel 3: sliding-window flash attention (all-internal bf16 buffers).
// Block: 256 thr, 32-query tile for one (b,h). K-blocks of 32 keys, <=17 per tile.
// LDS tiles bf16 (rows padded to 260). fp32 online softmax.
// ---------------------------------------------------------------------------
__global__ __launch_bounds__(256) void attn_kernel(
    const u16* __restrict__ Qb, const u16* __restrict__ Kb,
    const u16* __restrict__ Vb, u16* __restrict__ AO)
{
    const int i0 = blockIdx.x * 32;
    const int b  = blockIdx.y >> 2;
    const int h  = blockIdx.y & 3;
    const int t  = threadIdx.x;

    __shared__ __align__(16) u16 Qs[32][260];
    __shared__ __align__(16) u16 Ks[32][260];
    __shared__ __align__(16) u16 Vs[32][260];
    __shared__ float Sc[32][33];
    __shared__ float m_s[32], l_s[32], al_s[32];

    {
        const u16* qsrc = Qb + ((size_t)(b * 4096 + i0)) * 1024 + h * 256;
#pragma unroll
        for (int it = 0; it < 8; it++) {
            int idx = it * 1024 + t * 4;
            int r = idx >> 8, c = idx & 255;
            *(ushort4*)&Qs[r][c] = *(const ushort4*)(qsrc + (size_t)r * 1024 + c);
        }
    }
    if (t < 32) { m_s[t] = -1e30f; l_s[t] = 0.0f; }

    const int i2 = t >> 4, j2 = t & 15;      // score-phase layout
    const int qp = t >> 4, dc = t & 15;      // PV-phase layout
    const int qa = qp * 2, qbq = qp * 2 + 1;

    float oA[16], oB[16];
#pragma unroll
    for (int i = 0; i < 16; i++) { oA[i] = 0.0f; oB[i] = 0.0f; }

    int jb0 = i0 - 512; if (jb0 < 0) jb0 = 0;
    for (int jb = jb0; jb <= i0; jb += 32) {
        __syncthreads();   // previous PV done before overwriting K/V LDS
        const u16* ksrc = Kb + ((size_t)(b * 4096 + jb)) * 256;
        const u16* vsrc = Vb + ((size_t)(b * 4096 + jb)) * 256;
#pragma unroll
        for (int it = 0; it < 8; it++) {
            int idx = it * 1024 + t * 4;
            int r = idx >> 8, c = idx & 255;
            *(ushort4*)&Ks[r][c] = *(const ushort4*)(ksrc + (size_t)r * 256 + c);
            *(ushort4*)&Vs[r][c] = *(const ushort4*)(vsrc + (size_t)r * 256 + c);
        }
        __syncthreads();

        // ---- scores (2 queries x 2 keys per thread)
        float s00 = 0.f, s01 = 0.f, s10 = 0.f, s11 = 0.f;
        const u16* q0p = &Qs[i2 * 2][0];
        const u16* q1p = &Qs[i2 * 2 + 1][0];
        const u16* k0p = &Ks[j2 * 2][0];
        const u16* k1p = &Ks[j2 * 2 + 1][0];
#pragma unroll 8
        for (int d = 0; d < 256; d += 4) {
            ushort4 qv0 = *(const ushort4*)(q0p + d);
            ushort4 qv1 = *(const ushort4*)(q1p + d);
            ushort4 kv0 = *(const ushort4*)(k0p + d);
            ushort4 kv1 = *(const ushort4*)(k1p + d);
            float a0 = b2f(qv0.x), a1 = b2f(qv0.y), a2 = b2f(qv0.z), a3 = b2f(qv0.w);
            float b0 = b2f(qv1.x), b1 = b2f(qv1.y), b2 = b2f(qv1.z), b3 = b2f(qv1.w);
            float c0 = b2f(kv0.x), c1 = b2f(kv0.y), c2 = b2f(kv0.z), c3 = b2f(kv0.w);
            float e0 = b2f(kv1.x), e1 = b2f(kv1.y), e2 = b2f(kv1.z), e3 = b2f(kv1.w);
            s00 += a0 * c0 + a1 * c1 + a2 * c2 + a3 * c3;
            s01 += a0 * e0 + a1 * e1 + a2 * e2 + a3 * e3;
            s10 += b0 * c0 + b1 * c1 + b2 * c2 + b3 * c3;
            s11 += b0 * e0 + b1 * e1 + b2 * e2 + b3 * e3;
        }
        const int ia = i0 + i2 * 2, ibq = ia + 1;
        const int ja = jb + j2 * 2, jbg = ja + 1;
        Sc[i2 * 2 + 0][j2 * 2 + 0] = capmask(s00, ia,  ja);
        Sc[i2 * 2 + 0][j2 * 2 + 1] = capmask(s01, ia,  jbg);
        Sc[i2 * 2 + 1][j2 * 2 + 0] = capmask(s10, ibq, ja);
        Sc[i2 * 2 + 1][j2 * 2 + 1] = capmask(s11, ibq, jbg);
        __syncthreads();

        // ---- online softmax update (one thread per query row)
        if (t < 32) {
            float mo = m_s[t];
            float mb = -1e30f;
#pragma unroll
            for (int k = 0; k < 32; k++) mb = fmaxf(mb, Sc[t][k]);
            float mn = fmaxf(mo, mb);
            float alpha = __expf(mo - mn);   // both -1e30 -> exp(0)=1, l stays 0
            float sum = 0.f;
#pragma unroll
            for (int k = 0; k < 32; k++) {
                float svv = Sc[t][k];
                float pv = (svv > -1e29f) ? __expf(svv - mn) : 0.0f;  // masked -> 0
                Sc[t][k] = pv;
                sum += pv;
            }
            l_s[t] = l_s[t] * alpha + sum;
            m_s[t] = mn;
            al_s[t] = alpha;
        }
        __syncthreads();

        // ---- PV accumulate with rescale
        float aA = al_s[qa], aB = al_s[qbq];
#pragma unroll
        for (int i = 0; i < 16; i++) { oA[i] *= aA; oB[i] *= aB; }
#pragma unroll 4
        for (int kk = 0; kk < 32; kk++) {
            float pA = Sc[qa][kk], pB = Sc[qbq][kk];
            const u16* vrow = &Vs[kk][0];
#pragma unroll
            for (int c = 0; c < 4; c++) {
                ushort4 vv = *(const ushort4*)(vrow + c * 64 + dc * 4);
                float v0 = b2f(vv.x), v1 = b2f(vv.y), v2 = b2f(vv.z), v3 = b2f(vv.w);
                oA[c * 4 + 0] += pA * v0; oA[c * 4 + 1] += pA * v1;
                oA[c * 4 + 2] += pA * v2; oA[c * 4 + 3] += pA * v3;
                oB[c * 4 + 0] += pB * v0; oB[c * 4 + 1] += pB * v1;
                oB[c * 4 + 2] += pB * v2; oB[c * 4 + 3] += pB * v3;
            }
        }
    }

    float invA = 1.0f / l_s[qa];
    float invB = 1.0f / l_s[qbq];
    u16* pA = AO + ((size_t)(b * 4096 + i0 + qa))  * 1024 + h * 256;
    u16* pB = AO + ((size_t)(b * 4096 + i0 + qbq)) * 1024 + h * 256;
#pragma unroll
    for (int c = 0; c < 4; c++) {
        *(ushort4*)(pA + c * 64 + dc * 4) = make_ushort4(
            f2b(oA[c * 4 + 0] * invA), f2b(oA[c * 4 + 1] * invA),
            f2b(oA[c * 4 + 2] * invA), f2b(oA[c * 4 + 3] * invA));
        *(ushort4*)(pB + c * 64 + dc * 4) = make_ushort4(
            f2b(oB[c * 4 + 0] * invB), f2b(oB[c * 4 + 1] * invB),
            f2b(oB[c * 4 + 2] * invB), f2b(oB[c * 4 + 3] * invB));
    }
}

// ---------------------------------------------------------------------------
// Kernel 4: output projection.  out[8192 x 640] = AO[8192 x 1024] @ Wo[1024 x 640]
// A internal bf16; Wo dual-dtype; output dual-dtype (matches input world).
// ---------------------------------------------------------------------------
__global__ __launch_bounds__(256) void out_gemm(
    const u16* __restrict__ AO,
    const void* __restrict__ Wo,
    const void* __restrict__ cosT,
    void* __restrict__ outp)
{
    const bool isbf = detect_bf16(cosT);
    const int n0 = blockIdx.x * 128;
    const int m0 = blockIdx.y * 128;
    const int t  = threadIdx.x;

    __shared__ float As[8][128];
    __shared__ float Bs[8][128];

    const int tm = t >> 4, tn = t & 15;
    const int a_m = t >> 1;
    const int a_k = (t & 1) * 4;
    const int b_k = t >> 5;
    const int b_n = (t & 31) * 4;

    float acc[8][8];
#pragma unroll
    for (int i = 0; i < 8; i++)
#pragma unroll
        for (int j = 0; j < 8; j++) acc[i][j] = 0.0f;

    const u16* aptr = AO + (size_t)(m0 + a_m) * 1024 + a_k;
    const size_t b_off = (size_t)b_k * 640 + n0 + b_n;

    for (int kb = 0; kb < 1024; kb += 8) {
        ushort4 av = *(const ushort4*)(aptr + kb);
        float4 bv = ld4(Wo, b_off + (size_t)kb * 640, isbf);
        As[a_k + 0][a_m] = b2f(av.x);
        As[a_k + 1][a_m] = b2f(av.y);
        As[a_k + 2][a_m] = b2f(av.z);
        As[a_k + 3][a_m] = b2f(av.w);
        *(float4*)&Bs[b_k][b_n] = bv;
        __syncthreads();
#pragma unroll
        for (int kk = 0; kk < 8; kk++) {
            float a[8], b[8];
            *(float4*)&a[0] = *(const float4*)&As[kk][tm * 8];
            *(float4*)&a[4] = *(const float4*)&As[kk][tm * 8 + 4];
            *(float4*)&b[0] = *(const float4*)&Bs[kk][tn * 8];
            *(float4*)&b[4] = *(const float4*)&Bs[kk][tn * 8 + 4];
#pragma unroll
            for (int i = 0; i < 8; i++)
#pragma unroll
                for (int j = 0; j < 8; j++)
                    acc[i][j] += a[i] * b[j];
        }
        __syncthreads();
    }

#pragma unroll
    for (int i = 0; i < 8; i++) {
        int row = m0 + tm * 8 + i;
        size_t o = (size_t)row * 640 + n0 + tn * 8;
        if (isbf) {
            u16* p = (u16*)outp + o;
            *(ushort4*)p       = make_ushort4(f2b(acc[i][0]), f2b(acc[i][1]),
                                              f2b(acc[i][2]), f2b(acc[i][3]));
            *(ushort4*)(p + 4) = make_ushort4(f2b(acc[i][4]), f2b(acc[i][5]),
                                              f2b(acc[i][6]), f2b(acc[i][7]));
        } else {
            float* p = (float*)outp + o;
            *(float4*)p       = make_float4(acc[i][0], acc[i][1], acc[i][2], acc[i][3]);
            *(float4*)(p + 4) = make_float4(acc[i][4], acc[i][5], acc[i][6], acc[i][7]);
        }
    }
}

// ---------------------------------------------------------------------------
// Launch. Inputs: 0 hidden, 1 cos, 2 sin, 3 mask(UNUSED - analytic),
// 4 Wq, 5 Wk, 6 Wv, 7 Wo, 8 q_norm_w, 9 k_norm_w. Dtype (fp32 vs bf16)
// detected on-device from cos[0]==1.0 bit pattern; internal buffers bf16.
// Workspace (bf16): Qb 16MB | Kb 4MB | Vb 4MB | AO 16MB = 40MB total.
// ---------------------------------------------------------------------------
extern "C" void kernel_launch(void* const* d_in, const int* in_sizes, int n_in,
                              void* d_out, int out_size, void* d_ws, size_t ws_size,
                              hipStream_t stream) {
    const void* hidden = d_in[0];
    const void* cosT   = d_in[1];
    const void* sinT   = d_in[2];
    const void* Wq     = d_in[4];
    const void* Wk     = d_in[5];
    const void* Wv     = d_in[6];
    const void* Wo     = d_in[7];
    const void* qw     = d_in[8];
    const void* kw     = d_in[9];

    char* ws = (char*)d_ws;
    u16* Qb = (u16*)ws;                                  // 8192*1024
    u16* Kb = (u16*)(ws + 16777216);                     // 8192*256
    u16* Vb = (u16*)(ws + 16777216 + 4194304);           // 8192*256
    u16* AO = (u16*)(ws + 16777216 + 8388608);           // 8192*1024

    qkv_gemm<<<dim3(12, 64), 256, 0, stream>>>(hidden, Wq, Wk, Wv, cosT, Qb, Kb, Vb);
    norm_rope<<<dim3(8192), 320, 0, stream>>>(Qb, Kb, cosT, sinT, qw, kw);
    attn_kernel<<<dim3(128, 8), 256, 0, stream>>>(Qb, Kb, Vb, AO);
    out_gemm<<<dim3(5, 64), 256, 0, stream>>>(AO, Wo, cosT, d_out);
}

// Round 3
// 416.818 us; speedup vs baseline: 2.7177x; 2.7177x over previous
//
#include <hip/hip_runtime.h>

typedef unsigned short u16;
typedef unsigned int u32;

typedef __attribute__((ext_vector_type(8)))  short bf16x8;
typedef __attribute__((ext_vector_type(4)))  float f32x4;
typedef __attribute__((ext_vector_type(16))) float f32x16;

__device__ __forceinline__ float b2f(u16 u) {
    union { unsigned int i; float f; } v; v.i = ((unsigned int)u) << 16; return v.f;
}
__device__ __forceinline__ u16 f2b(float f) {
    union { float ff; unsigned int i; } v; v.ff = f;
    unsigned int x = v.i;
    return (u16)((x + 0x7fffu + ((x >> 16) & 1u)) >> 16);
}
__device__ __forceinline__ bool detect_bf16(const void* cosT) {
    // cos row 0 is all 1.0: fp32 word = 0x3F800000, bf16 pair = 0x3F803F80
    return ((*(const u32*)cosT) & 0xffffu) == 0x3f80u;
}
__device__ __forceinline__ float4 ld4(const void* p, size_t off, bool isbf) {
    if (isbf) {
        ushort4 v = *(const ushort4*)((const u16*)p + off);
        return make_float4(b2f(v.x), b2f(v.y), b2f(v.z), b2f(v.w));
    }
    return *(const float4*)((const float*)p + off);
}
__device__ __forceinline__ float lds(const void* p, size_t off, bool isbf) {
    return isbf ? b2f(((const u16*)p)[off]) : ((const float*)p)[off];
}
// softcap + sliding-window mask. SCALING = 1/16, SOFTCAP = 50.
__device__ __forceinline__ float capmask(float sdot, int i, int j) {
    float v = sdot * (0.0625f / 50.0f);
    v = fminf(fmaxf(v, -10.0f), 10.0f);
    float e = __expf(2.0f * v);
    float c = 50.0f * (e - 1.0f) / (e + 1.0f);
    bool allowed = (j <= i) && (j > i - 512);
    return allowed ? c : -1e30f;
}

// ---------------------------------------------------------------------------
// K0: hidden fp32/bf16 -> bf16 workspace (8192*640)
// ---------------------------------------------------------------------------
__global__ __launch_bounds__(256) void conv_hidden(
    const void* __restrict__ src, const void* __restrict__ cosT, u16* __restrict__ dst)
{
    const bool isbf = detect_bf16(cosT);
    size_t base = ((size_t)blockIdx.x * 256 + threadIdx.x) * 8;
    if (isbf) {
        *(uint4*)(dst + base) = *(const uint4*)((const u16*)src + base);
    } else {
        float4 a = ld4(src, base, false);
        float4 b = ld4(src, base + 4, false);
        uint4 o;
        o.x = (u32)f2b(a.x) | ((u32)f2b(a.y) << 16);
        o.y = (u32)f2b(a.z) | ((u32)f2b(a.w) << 16);
        o.z = (u32)f2b(b.x) | ((u32)f2b(b.y) << 16);
        o.w = (u32)f2b(b.z) | ((u32)f2b(b.w) << 16);
        *(uint4*)(dst + base) = o;
    }
}

// ---------------------------------------------------------------------------
// K1: build transposed bf16 weights.
//   WT [1536][640] = [Wq|Wk|Wv]^T   (row n = output dim, col k = input dim)
//   WoT[640][1024] = Wo^T
// 32x32 LDS-tiled transpose, 256 thr (32x8). tiles: 960 (WT) + 640 (WoT).
// ---------------------------------------------------------------------------
__global__ __launch_bounds__(256) void transpose_w(
    const void* __restrict__ Wq, const void* __restrict__ Wk,
    const void* __restrict__ Wv, const void* __restrict__ Wo,
    const void* __restrict__ cosT,
    u16* __restrict__ WT, u16* __restrict__ WoT)
{
    const bool isbf = detect_bf16(cosT);
    __shared__ float T[32][33];
    const int tx = threadIdx.x & 31, ty = threadIdx.x >> 5;
    int id = blockIdx.x;
    if (id < 960) {                       // WT tile: n0 = (id%48)*32, k0 = (id/48)*32
        const int n0 = (id % 48) * 32, k0 = (id / 48) * 32;
        const void* src; int ldw, nof;
        if (n0 < 1024)      { src = Wq; ldw = 1024; nof = n0; }
        else if (n0 < 1280) { src = Wk; ldw = 256;  nof = n0 - 1024; }
        else                { src = Wv; ldw = 256;  nof = n0 - 1280; }
#pragma unroll
        for (int j = 0; j < 4; j++)
            T[ty + 8 * j][tx] = lds(src, (size_t)(k0 + ty + 8 * j) * ldw + nof + tx, isbf);
        __syncthreads();
#pragma unroll
        for (int j = 0; j < 4; j++)
            WT[(size_t)(n0 + ty + 8 * j) * 640 + k0 + tx] = f2b(T[tx][ty + 8 * j]);
    } else {                              // WoT tile
        id -= 960;
        const int k0 = (id & 31) * 32, n0 = (id >> 5) * 32;
#pragma unroll
        for (int j = 0; j < 4; j++)
            T[ty + 8 * j][tx] = lds(Wo, (size_t)(k0 + ty + 8 * j) * 640 + n0 + tx, isbf);
        __syncthreads();
#pragma unroll
        for (int j = 0; j < 4; j++)
            WoT[(size_t)(n0 + ty + 8 * j) * 1024 + k0 + tx] = f2b(T[tx][ty + 8 * j]);
    }
}

// ---------------------------------------------------------------------------
// K2: QKV GEMM (MFMA bf16).  C[8192 x 1536] = Hb[8192 x 640] @ WT^T
// 128x128 tile, BK=32, 256 thr = 4 waves (2x2 of 64x64), 16x16x32 MFMA.
// Output: cols <1024 -> Qb, <1280 -> Kb, else V written TRANSPOSED to Vt_g.
// ---------------------------------------------------------------------------
__global__ __launch_bounds__(256) void qkv_gemm(
    const u16* __restrict__ Hb, const u16* __restrict__ WT,
    u16* __restrict__ Qb, u16* __restrict__ Kb, u16* __restrict__ Vtg)
{
    const int n0 = blockIdx.x * 128, m0 = blockIdx.y * 128;
    const int t = threadIdx.x, w = t >> 6, lane = t & 63;
    const int l15 = lane & 15, quad = lane >> 4;
    const int wm = (w & 1) * 64, wn = (w >> 1) * 64;

    __shared__ __align__(16) u16 Ah[128][32];
    __shared__ __align__(16) u16 Bh[128][32];

    f32x4 acc[4][4];
#pragma unroll
    for (int i = 0; i < 4; i++)
#pragma unroll
        for (int j = 0; j < 4; j++) acc[i][j] = (f32x4)0.0f;

    for (int kb = 0; kb < 640; kb += 32) {
        __syncthreads();
#pragma unroll
        for (int i = 0; i < 2; i++) {
            int ci = t + 256 * i, m = ci >> 2, c = ci & 3;
            *(uint4*)&Ah[m][c * 8] = *(const uint4*)(Hb + (size_t)(m0 + m) * 640 + kb + c * 8);
            *(uint4*)&Bh[m][c * 8] = *(const uint4*)(WT + (size_t)(n0 + m) * 640 + kb + c * 8);
        }
        __syncthreads();
        bf16x8 af[4], bfr[4];
#pragma unroll
        for (int mi = 0; mi < 4; mi++)
            af[mi] = *(const bf16x8*)&Ah[wm + mi * 16 + l15][quad * 8];
#pragma unroll
        for (int ni = 0; ni < 4; ni++)
            bfr[ni] = *(const bf16x8*)&Bh[wn + ni * 16 + l15][quad * 8];
#pragma unroll
        for (int mi = 0; mi < 4; mi++)
#pragma unroll
            for (int ni = 0; ni < 4; ni++)
                acc[mi][ni] = __builtin_amdgcn_mfma_f32_16x16x32_bf16(
                    af[mi], bfr[ni], acc[mi][ni], 0, 0, 0);
    }

    const int bb = m0 >> 12, sblk = m0 & 4095;
#pragma unroll
    for (int mi = 0; mi < 4; mi++)
#pragma unroll
        for (int ni = 0; ni < 4; ni++) {
            int rowb = m0 + wm + mi * 16 + quad * 4;
            int col  = n0 + wn + ni * 16 + l15;
            if (n0 < 1024) {
#pragma unroll
                for (int r = 0; r < 4; r++)
                    Qb[(size_t)(rowb + r) * 1024 + col] = f2b(acc[mi][ni][r]);
            } else if (n0 < 1280) {
#pragma unroll
                for (int r = 0; r < 4; r++)
                    Kb[(size_t)(rowb + r) * 256 + (col - 1024)] = f2b(acc[mi][ni][r]);
            } else {
                int vd = col - 1280;
                int sb = sblk + wm + mi * 16 + quad * 4;
                ushort4 vv = make_ushort4(f2b(acc[mi][ni][0]), f2b(acc[mi][ni][1]),
                                          f2b(acc[mi][ni][2]), f2b(acc[mi][ni][3]));
                *(ushort4*)(Vtg + (size_t)bb * 1048576 + (size_t)vd * 4096 + sb) = vv;
            }
        }
}

// ---------------------------------------------------------------------------
// K3: fused RMS-norm + RoPE in place on Qb (4 heads) and Kb (1 head).
// ---------------------------------------------------------------------------
__global__ __launch_bounds__(320) void norm_rope(
    u16* __restrict__ Qb, u16* __restrict__ Kb,
    const void* __restrict__ cosT, const void* __restrict__ sinT,
    const void* __restrict__ qw, const void* __restrict__ kw)
{
    const bool isbf = detect_bf16(cosT);
    const int row = blockIdx.x, s = row & 4095;
    const int g = threadIdx.x >> 6, lane = threadIdx.x & 63, d0 = lane * 4;

    u16* p; const void* w;
    if (g < 4) { p = Qb + (size_t)row * 1024 + g * 256 + d0; w = qw; }
    else       { p = Kb + (size_t)row * 256 + d0;            w = kw; }

    ushort4 xv = *(const ushort4*)p;
    float x0 = b2f(xv.x), x1 = b2f(xv.y), x2 = b2f(xv.z), x3 = b2f(xv.w);
    float ssum = x0 * x0 + x1 * x1 + x2 * x2 + x3 * x3;
#pragma unroll
    for (int off = 32; off > 0; off >>= 1) ssum += __shfl_xor(ssum, off, 64);
    float rs = rsqrtf(ssum * (1.0f / 256.0f) + 1e-6f);

    float4 wv = ld4(w, d0, isbf);
    float n0 = x0 * rs * (1.0f + wv.x);
    float n1 = x1 * rs * (1.0f + wv.y);
    float n2 = x2 * rs * (1.0f + wv.z);
    float n3 = x3 * rs * (1.0f + wv.w);

    float o0 = __shfl_xor(n0, 32, 64);
    float o1 = __shfl_xor(n1, 32, 64);
    float o2 = __shfl_xor(n2, 32, 64);
    float o3 = __shfl_xor(n3, 32, 64);
    float sgn = (lane < 32) ? -1.0f : 1.0f;

    float4 cv = ld4(cosT, (size_t)s * 256 + d0, isbf);
    float4 sv = ld4(sinT, (size_t)s * 256 + d0, isbf);
    *(ushort4*)p = make_ushort4(
        f2b(n0 * cv.x + sgn * o0 * sv.x), f2b(n1 * cv.y + sgn * o1 * sv.y),
        f2b(n2 * cv.z + sgn * o2 * sv.z), f2b(n3 * cv.w + sgn * o3 * sv.w));
}

// ---------------------------------------------------------------------------
// K4: sliding-window flash attention, 32x32x16 MFMA.
// Block = (b, h, 64 queries), 128 thr = 2 waves x 32 queries. kv-blocks of 32.
// Fixed-max softmax (softcap bounds |s|<=50 -> exp(s) in fp32 range): no
// running max / rescale. P -> LDS (bf16) -> B-operand of O^T = V^T * P^T.
// C/D 32x32 layout: col=lane&31, row=(reg&3)+8*(reg>>2)+4*(lane>>5).
// ---------------------------------------------------------------------------
__global__ __launch_bounds__(128, 2) void attn_mfma(
    const u16* __restrict__ Qb, const u16* __restrict__ Kb,
    const u16* __restrict__ Vtg, u16* __restrict__ AO)
{
    const int qb = blockIdx.x * 64;
    const int b = blockIdx.y >> 2, h = blockIdx.y & 3;
    const int t = threadIdx.x, w = t >> 6, lane = t & 63;
    const int hi = lane >> 5, m32 = lane & 31;
    const int qw0 = qb + w * 32;

    __shared__ __align__(16) u16 Ks[32][264];
    __shared__ __align__(16) u16 Vt[256][40];
    __shared__ __align__(16) u16 Pr[2][32][40];
    __shared__ float l_s[2][32];

    // Q fragments (A-operand, 32x32x16): lane holds Q[m32][ks*16 + hi*8 + j]
    bf16x8 qf[16];
    {
        const u16* qp = Qb + ((size_t)(b * 4096 + qw0 + m32)) * 1024 + h * 256 + hi * 8;
#pragma unroll
        for (int s = 0; s < 16; s++) qf[s] = *(const bf16x8*)(qp + s * 16);
    }

    f32x16 o[8];
#pragma unroll
    for (int i = 0; i < 8; i++) o[i] = (f32x16)0.0f;
    float lp[16];
#pragma unroll
    for (int i = 0; i < 16; i++) lp[i] = 0.0f;

    int lo = qb - 511;
    int jb0 = lo > 0 ? (lo & ~31) : 0;
    for (int jb = jb0; jb <= qb + 63; jb += 32) {
        __syncthreads();
        // stage K [32 keys][256 d] and Vt [256 d][32 keys] (from Vt_g)
#pragma unroll
        for (int i = 0; i < 8; i++) {
            int ci = t + 128 * i;
            int key = ci >> 5, c = ci & 31;
            *(uint4*)&Ks[key][c * 8] =
                *(const uint4*)(Kb + ((size_t)(b * 4096 + jb + key)) * 256 + c * 8);
            int d = ci >> 2, c2 = ci & 3;
            *(uint4*)&Vt[d][c2 * 8] =
                *(const uint4*)(Vtg + (size_t)b * 1048576 + (size_t)d * 4096 + jb + c2 * 8);
        }
        __syncthreads();

        bool active = !(jb > qw0 + 31 || jb + 31 < qw0 - 511);
        if (active) {
            // ---- S = Q K^T (32 queries x 32 keys), K-steps over d
            f32x16 s = (f32x16)0.0f;
#pragma unroll
            for (int ks = 0; ks < 16; ks++) {
                bf16x8 kf = *(const bf16x8*)&Ks[m32][ks * 16 + hi * 8];
                s = __builtin_amdgcn_mfma_f32_32x32x16_bf16(qf[ks], kf, s, 0, 0, 0);
            }
            // ---- softcap + mask + exp (fixed max), write P to LDS
            int j = jb + m32;
#pragma unroll
            for (int r = 0; r < 16; r++) {
                int qrow = (r & 3) + 8 * (r >> 2) + 4 * hi;
                float c = capmask(s[r], qw0 + qrow, j);
                float p = __expf(c);
                u16 pb = f2b(p);
                Pr[w][qrow][m32] = pb;
                lp[r] += b2f(pb);
            }
            __threadfence_block();
            // ---- O^T += V^T P^T
            bf16x8 pf0 = *(const bf16x8*)&Pr[w][m32][hi * 8];
            bf16x8 pf1 = *(const bf16x8*)&Pr[w][m32][16 + hi * 8];
#pragma unroll
            for (int mt = 0; mt < 8; mt++) {
                bf16x8 v0 = *(const bf16x8*)&Vt[mt * 32 + m32][hi * 8];
                bf16x8 v1 = *(const bf16x8*)&Vt[mt * 32 + m32][16 + hi * 8];
                o[mt] = __builtin_amdgcn_mfma_f32_32x32x16_bf16(v0, pf0, o[mt], 0, 0, 0);
                o[mt] = __builtin_amdgcn_mfma_f32_32x32x16_bf16(v1, pf1, o[mt], 0, 0, 0);
            }
        }
    }

    // ---- reduce l across the 32 key-lanes, redistribute to query-col layout
#pragma unroll
    for (int r = 0; r < 16; r++) {
        float v = lp[r];
        v += __shfl_xor(v, 1, 64); v += __shfl_xor(v, 2, 64);
        v += __shfl_xor(v, 4, 64); v += __shfl_xor(v, 8, 64);
        v += __shfl_xor(v, 16, 64);
        lp[r] = v;
    }
    __syncthreads();
    if (m32 == 0) {
#pragma unroll
        for (int r = 0; r < 16; r++)
            l_s[w][(r & 3) + 8 * (r >> 2) + 4 * hi] = lp[r];
    }
    __syncthreads();
    float inv = 1.0f / l_s[w][m32];

    u16* aop = AO + ((size_t)(b * 4096 + qw0 + m32)) * 1024 + h * 256;
#pragma unroll
    for (int mt = 0; mt < 8; mt++)
#pragma unroll
        for (int g = 0; g < 4; g++) {
            ushort4 vv = make_ushort4(
                f2b(o[mt][g * 4 + 0] * inv), f2b(o[mt][g * 4 + 1] * inv),
                f2b(o[mt][g * 4 + 2] * inv), f2b(o[mt][g * 4 + 3] * inv));
            *(ushort4*)(aop + mt * 32 + g * 8 + hi * 4) = vv;
        }
}

// ---------------------------------------------------------------------------
// K5: output projection (MFMA bf16). out[8192 x 640] = AO[8192 x 1024] @ Wo
// B from WoT[640][1024]. Output dtype follows input world (fp32 or bf16).
// ---------------------------------------------------------------------------
__global__ __launch_bounds__(256) void out_gemm(
    const u16* __restrict__ AO, const u16* __restrict__ WoT,
    const void* __restrict__ cosT, void* __restrict__ outp)
{
    const bool isbf = detect_bf16(cosT);
    const int n0 = blockIdx.x * 128, m0 = blockIdx.y * 128;
    const int t = threadIdx.x, w = t >> 6, lane = t & 63;
    const int l15 = lane & 15, quad = lane >> 4;
    const int wm = (w & 1) * 64, wn = (w >> 1) * 64;

    __shared__ __align__(16) u16 Ah[128][32];
    __shared__ __align__(16) u16 Bh[128][32];

    f32x4 acc[4][4];
#pragma unroll
    for (int i = 0; i < 4; i++)
#pragma unroll
        for (int j = 0; j < 4; j++) acc[i][j] = (f32x4)0.0f;

    for (int kb = 0; kb < 1024; kb += 32) {
        __syncthreads();
#pragma unroll
        for (int i = 0; i < 2; i++) {
            int ci = t + 256 * i, m = ci >> 2, c = ci & 3;
            *(uint4*)&Ah[m][c * 8] = *(const uint4*)(AO + (size_t)(m0 + m) * 1024 + kb + c * 8);
            *(uint4*)&Bh[m][c * 8] = *(const uint4*)(WoT + (size_t)(n0 + m) * 1024 + kb + c * 8);
        }
        __syncthreads();
        bf16x8 af[4], bfr[4];
#pragma unroll
        for (int mi = 0; mi < 4; mi++)
            af[mi] = *(const bf16x8*)&Ah[wm + mi * 16 + l15][quad * 8];
#pragma unroll
        for (int ni = 0; ni < 4; ni++)
            bfr[ni] = *(const bf16x8*)&Bh[wn + ni * 16 + l15][quad * 8];
#pragma unroll
        for (int mi = 0; mi < 4; mi++)
#pragma unroll
            for (int ni = 0; ni < 4; ni++)
                acc[mi][ni] = __builtin_amdgcn_mfma_f32_16x16x32_bf16(
                    af[mi], bfr[ni], acc[mi][ni], 0, 0, 0);
    }

#pragma unroll
    for (int mi = 0; mi < 4; mi++)
#pragma unroll
        for (int ni = 0; ni < 4; ni++) {
            int rowb = m0 + wm + mi * 16 + quad * 4;
            int col  = n0 + wn + ni * 16 + l15;
            if (isbf) {
#pragma unroll
                for (int r = 0; r < 4; r++)
                    ((u16*)outp)[(size_t)(rowb + r) * 640 + col] = f2b(acc[mi][ni][r]);
            } else {
#pragma unroll
                for (int r = 0; r < 4; r++)
                    ((float*)outp)[(size_t)(rowb + r) * 640 + col] = acc[mi][ni][r];
            }
        }
}

// ---------------------------------------------------------------------------
// Launch. Inputs: 0 hidden, 1 cos, 2 sin, 3 mask(UNUSED), 4 Wq, 5 Wk, 6 Wv,
// 7 Wo, 8 q_norm_w, 9 k_norm_w. Workspace (43.3 MB, AO overlays Hb+WT):
//   [0, 16.78M): Hb(10.49M) + WT(1.97M)  -- dead after GEMMs; AO reuses @0
//   [16.78M): WoT 1.31M | Qb 16.78M | Kb 4.19M | Vt_g 4.19M
// ---------------------------------------------------------------------------
extern "C" void kernel_launch(void* const* d_in, const int* in_sizes, int n_in,
                              void* d_out, int out_size, void* d_ws, size_t ws_size,
                              hipStream_t stream) {
    const void* hidden = d_in[0];
    const void* cosT   = d_in[1];
    const void* sinT   = d_in[2];
    const void* Wq     = d_in[4];
    const void* Wk     = d_in[5];
    const void* Wv     = d_in[6];
    const void* Wo     = d_in[7];
    const void* qw     = d_in[8];
    const void* kw     = d_in[9];

    char* ws = (char*)d_ws;
    u16* Hb  = (u16*)ws;                            // 8192*640
    u16* WT  = (u16*)(ws + 10485760);               // 1536*640
    u16* AO  = (u16*)ws;                            // 8192*1024 (overlays Hb/WT)
    u16* WoT = (u16*)(ws + 16777216);               // 640*1024
    u16* Qb  = (u16*)(ws + 18087936);               // 8192*1024
    u16* Kb  = (u16*)(ws + 34865152);               // 8192*256
    u16* Vtg = (u16*)(ws + 39059456);               // 2*256*4096

    conv_hidden<<<dim3(2560), 256, 0, stream>>>(hidden, cosT, Hb);
    transpose_w<<<dim3(1600), 256, 0, stream>>>(Wq, Wk, Wv, Wo, cosT, WT, WoT);
    qkv_gemm<<<dim3(12, 64), 256, 0, stream>>>(Hb, WT, Qb, Kb, Vtg);
    norm_rope<<<dim3(8192), 320, 0, stream>>>(Qb, Kb, cosT, sinT, qw, kw);
    attn_mfma<<<dim3(64, 8), 128, 0, stream>>>(Qb, Kb, Vtg, AO);
    out_gemm<<<dim3(5, 64), 256, 0, stream>>>(AO, WoT, cosT, d_out);
}

// Round 4
// 340.688 us; speedup vs baseline: 3.3251x; 1.2235x over previous
//
#include <hip/hip_runtime.h>

typedef unsigned short u16;
typedef unsigned int u32;

typedef __attribute__((ext_vector_type(8)))  short bf16x8;
typedef __attribute__((ext_vector_type(4)))  float f32x4;

__device__ __forceinline__ float b2f(u16 u) {
    union { unsigned int i; float f; } v; v.i = ((unsigned int)u) << 16; return v.f;
}
__device__ __forceinline__ u16 f2b(float f) {
    union { float ff; unsigned int i; } v; v.ff = f;
    unsigned int x = v.i;
    return (u16)((x + 0x7fffu + ((x >> 16) & 1u)) >> 16);
}
__device__ __forceinline__ bool detect_bf16(const void* cosT) {
    // cos row 0 is all 1.0: fp32 word = 0x3F800000, bf16 pair = 0x3F803F80
    return ((*(const u32*)cosT) & 0xffffu) == 0x3f80u;
}
__device__ __forceinline__ float4 ld4(const void* p, size_t off, bool isbf) {
    if (isbf) {
        ushort4 v = *(const ushort4*)((const u16*)p + off);
        return make_float4(b2f(v.x), b2f(v.y), b2f(v.z), b2f(v.w));
    }
    return *(const float4*)((const float*)p + off);
}
__device__ __forceinline__ float lds1(const void* p, size_t off, bool isbf) {
    return isbf ? b2f(((const u16*)p)[off]) : ((const float*)p)[off];
}
// async 16B global -> LDS (dest = wave-uniform base + lane*16)
__device__ __forceinline__ void gll16(const void* g, void* l) {
    __builtin_amdgcn_global_load_lds(
        (const __attribute__((address_space(1))) u32*)g,
        (__attribute__((address_space(3))) u32*)l, 16, 0, 0);
}
// softcap + sliding-window mask. SCALING = 1/16, SOFTCAP = 50.
// masked -> -1e30, and expf(-1e30) underflows to exactly 0.
__device__ __forceinline__ float capmask(float sdot, int i, int j) {
    float v = sdot * (0.0625f / 50.0f);
    v = fminf(fmaxf(v, -10.0f), 10.0f);
    float e = __expf(2.0f * v);
    float c = 50.0f * (e - 1.0f) / (e + 1.0f);
    bool allowed = (j <= i) && (j > i - 512);
    return allowed ? c : -1e30f;
}

// ---------------------------------------------------------------------------
// K0: hidden fp32/bf16 -> bf16 workspace (8192*640)
// ---------------------------------------------------------------------------
__global__ __launch_bounds__(256) void conv_hidden(
    const void* __restrict__ src, const void* __restrict__ cosT, u16* __restrict__ dst)
{
    const bool isbf = detect_bf16(cosT);
    size_t base = ((size_t)blockIdx.x * 256 + threadIdx.x) * 8;
    if (isbf) {
        *(uint4*)(dst + base) = *(const uint4*)((const u16*)src + base);
    } else {
        float4 a = ld4(src, base, false);
        float4 b = ld4(src, base + 4, false);
        uint4 o;
        o.x = (u32)f2b(a.x) | ((u32)f2b(a.y) << 16);
        o.y = (u32)f2b(a.z) | ((u32)f2b(a.w) << 16);
        o.z = (u32)f2b(b.x) | ((u32)f2b(b.y) << 16);
        o.w = (u32)f2b(b.z) | ((u32)f2b(b.w) << 16);
        *(uint4*)(dst + base) = o;
    }
}

// ---------------------------------------------------------------------------
// K1: build transposed bf16 weights. WT[1536][640], WoT[640][1024].
// ---------------------------------------------------------------------------
__global__ __launch_bounds__(256) void transpose_w(
    const void* __restrict__ Wq, const void* __restrict__ Wk,
    const void* __restrict__ Wv, const void* __restrict__ Wo,
    const void* __restrict__ cosT,
    u16* __restrict__ WT, u16* __restrict__ WoT)
{
    const bool isbf = detect_bf16(cosT);
    __shared__ float T[32][33];
    const int tx = threadIdx.x & 31, ty = threadIdx.x >> 5;
    int id = blockIdx.x;
    if (id < 960) {
        const int n0 = (id % 48) * 32, k0 = (id / 48) * 32;
        const void* src; int ldw, nof;
        if (n0 < 1024)      { src = Wq; ldw = 1024; nof = n0; }
        else if (n0 < 1280) { src = Wk; ldw = 256;  nof = n0 - 1024; }
        else                { src = Wv; ldw = 256;  nof = n0 - 1280; }
#pragma unroll
        for (int j = 0; j < 4; j++)
            T[ty + 8 * j][tx] = lds1(src, (size_t)(k0 + ty + 8 * j) * ldw + nof + tx, isbf);
        __syncthreads();
#pragma unroll
        for (int j = 0; j < 4; j++)
            WT[(size_t)(n0 + ty + 8 * j) * 640 + k0 + tx] = f2b(T[tx][ty + 8 * j]);
    } else {
        id -= 960;
        const int k0 = (id & 31) * 32, n0 = (id >> 5) * 32;
#pragma unroll
        for (int j = 0; j < 4; j++)
            T[ty + 8 * j][tx] = lds1(Wo, (size_t)(k0 + ty + 8 * j) * 640 + n0 + tx, isbf);
        __syncthreads();
#pragma unroll
        for (int j = 0; j < 4; j++)
            WoT[(size_t)(n0 + ty + 8 * j) * 1024 + k0 + tx] = f2b(T[tx][ty + 8 * j]);
    }
}

// ---------------------------------------------------------------------------
// K2: QKV GEMM (MFMA bf16 + global_load_lds staging).
// 128x128 tile, BK=32, 4 waves (2x2 of 64x64), 16x16x32 MFMA.
// ---------------------------------------------------------------------------
__global__ __launch_bounds__(256) void qkv_gemm(
    const u16* __restrict__ Hb, const u16* __restrict__ WT,
    u16* __restrict__ Qb, u16* __restrict__ Kb, u16* __restrict__ Vtg)
{
    const int n0 = blockIdx.x * 128, m0 = blockIdx.y * 128;
    const int t = threadIdx.x, w = t >> 6, lane = t & 63;
    const int l15 = lane & 15, quad = lane >> 4;
    const int wm = (w & 1) * 64, wn = (w >> 1) * 64;

    __shared__ __align__(16) u16 Ah[128][32];
    __shared__ __align__(16) u16 Bh[128][32];

    f32x4 acc[4][4];
#pragma unroll
    for (int i = 0; i < 4; i++)
#pragma unroll
        for (int j = 0; j < 4; j++) acc[i][j] = (f32x4)0.0f;

    for (int kb = 0; kb < 640; kb += 32) {
        __syncthreads();
#pragma unroll
        for (int i = 0; i < 2; i++) {
            int ci = t + 256 * i, m = ci >> 2, c = ci & 3;
            gll16(Hb + (size_t)(m0 + m) * 640 + kb + c * 8, (char*)&Ah[0][0] + ci * 16);
            gll16(WT + (size_t)(n0 + m) * 640 + kb + c * 8, (char*)&Bh[0][0] + ci * 16);
        }
        __syncthreads();
        bf16x8 af[4], bfr[4];
#pragma unroll
        for (int mi = 0; mi < 4; mi++)
            af[mi] = *(const bf16x8*)&Ah[wm + mi * 16 + l15][quad * 8];
#pragma unroll
        for (int ni = 0; ni < 4; ni++)
            bfr[ni] = *(const bf16x8*)&Bh[wn + ni * 16 + l15][quad * 8];
#pragma unroll
        for (int mi = 0; mi < 4; mi++)
#pragma unroll
            for (int ni = 0; ni < 4; ni++)
                acc[mi][ni] = __builtin_amdgcn_mfma_f32_16x16x32_bf16(
                    af[mi], bfr[ni], acc[mi][ni], 0, 0, 0);
    }

    const int bb = m0 >> 12, sblk = m0 & 4095;
#pragma unroll
    for (int mi = 0; mi < 4; mi++)
#pragma unroll
        for (int ni = 0; ni < 4; ni++) {
            int rowb = m0 + wm + mi * 16 + quad * 4;
            int col  = n0 + wn + ni * 16 + l15;
            if (n0 < 1024) {
#pragma unroll
                for (int r = 0; r < 4; r++)
                    Qb[(size_t)(rowb + r) * 1024 + col] = f2b(acc[mi][ni][r]);
            } else if (n0 < 1280) {
#pragma unroll
                for (int r = 0; r < 4; r++)
                    Kb[(size_t)(rowb + r) * 256 + (col - 1024)] = f2b(acc[mi][ni][r]);
            } else {
                int vd = col - 1280;
                int sb = sblk + wm + mi * 16 + quad * 4;
                ushort4 vv = make_ushort4(f2b(acc[mi][ni][0]), f2b(acc[mi][ni][1]),
                                          f2b(acc[mi][ni][2]), f2b(acc[mi][ni][3]));
                *(ushort4*)(Vtg + (size_t)bb * 1048576 + (size_t)vd * 4096 + sb) = vv;
            }
        }
}

// ---------------------------------------------------------------------------
// K3: fused RMS-norm + RoPE in place on Qb (4 heads) and Kb (1 head).
// ---------------------------------------------------------------------------
__global__ __launch_bounds__(320) void norm_rope(
    u16* __restrict__ Qb, u16* __restrict__ Kb,
    const void* __restrict__ cosT, const void* __restrict__ sinT,
    const void* __restrict__ qw, const void* __restrict__ kw)
{
    const bool isbf = detect_bf16(cosT);
    const int row = blockIdx.x, s = row & 4095;
    const int g = threadIdx.x >> 6, lane = threadIdx.x & 63, d0 = lane * 4;

    u16* p; const void* w;
    if (g < 4) { p = Qb + (size_t)row * 1024 + g * 256 + d0; w = qw; }
    else       { p = Kb + (size_t)row * 256 + d0;            w = kw; }

    ushort4 xv = *(const ushort4*)p;
    float x0 = b2f(xv.x), x1 = b2f(xv.y), x2 = b2f(xv.z), x3 = b2f(xv.w);
    float ssum = x0 * x0 + x1 * x1 + x2 * x2 + x3 * x3;
#pragma unroll
    for (int off = 32; off > 0; off >>= 1) ssum += __shfl_xor(ssum, off, 64);
    float rs = rsqrtf(ssum * (1.0f / 256.0f) + 1e-6f);

    float4 wv = ld4(w, d0, isbf);
    float n0 = x0 * rs * (1.0f + wv.x);
    float n1 = x1 * rs * (1.0f + wv.y);
    float n2 = x2 * rs * (1.0f + wv.z);
    float n3 = x3 * rs * (1.0f + wv.w);

    float o0 = __shfl_xor(n0, 32, 64);
    float o1 = __shfl_xor(n1, 32, 64);
    float o2 = __shfl_xor(n2, 32, 64);
    float o3 = __shfl_xor(n3, 32, 64);
    float sgn = (lane < 32) ? -1.0f : 1.0f;

    float4 cv = ld4(cosT, (size_t)s * 256 + d0, isbf);
    float4 sv = ld4(sinT, (size_t)s * 256 + d0, isbf);
    *(ushort4*)p = make_ushort4(
        f2b(n0 * cv.x + sgn * o0 * sv.x), f2b(n1 * cv.y + sgn * o1 * sv.y),
        f2b(n2 * cv.z + sgn * o2 * sv.z), f2b(n3 * cv.w + sgn * o3 * sv.w));
}

// ---------------------------------------------------------------------------
// K4: sliding-window flash attention, 16x16x32 MFMA.
// Block = 256 thr = 4 waves = 4 heads x SAME 16 queries (NKV=1: K/V shared).
// Grid = (S/16, B) = (256, 2) -> 512 blocks x 4 waves = 8 waves/CU.
// Per kv-iter (32 keys): stage K[32][256] + Vt[256][32] once for all heads.
// Fixed-max softmax (softcap bounds |s|<=50). P -> per-wave LDS -> B-operand
// of O^T = V^T P^T. 16x16 C/D: col=lane&15, row=(lane>>4)*4+reg.
// ---------------------------------------------------------------------------
__global__ __launch_bounds__(256, 2) void attn_mfma(
    const u16* __restrict__ Qb, const u16* __restrict__ Kb,
    const u16* __restrict__ Vtg, u16* __restrict__ AO)
{
    const int q0 = blockIdx.x * 16;
    const int b  = blockIdx.y;
    const int t = threadIdx.x, h = t >> 6, lane = t & 63;
    const int l15 = lane & 15, quad = lane >> 4;

    __shared__ __align__(16) u16 Ks[32][264];
    __shared__ __align__(16) u16 Vt[256][40];
    __shared__ __align__(16) u16 Pr[4][16][40];
    __shared__ float l_s[4][16];

    // Q A-fragments: lane: q = q0+l15, d = quad*8 + dstep*32 + j
    bf16x8 qf[8];
    {
        const u16* qp = Qb + ((size_t)(b * 4096 + q0 + l15)) * 1024 + h * 256 + quad * 8;
#pragma unroll
        for (int s = 0; s < 8; s++) qf[s] = *(const bf16x8*)(qp + s * 32);
    }

    f32x4 o[16];
#pragma unroll
    for (int i = 0; i < 16; i++) o[i] = (f32x4)0.0f;
    float lp[4] = {0.f, 0.f, 0.f, 0.f};

    int lo = q0 - 511;
    const int jb0 = lo > 0 ? (lo >> 5) << 5 : 0;
    const int jb1 = (q0 + 15) & ~31;
    for (int jb = jb0; jb <= jb1; jb += 32) {
        __syncthreads();
        // stage K [32 keys][256 d] and Vt [256 d][32 keys], shared by 4 heads
#pragma unroll
        for (int i = 0; i < 4; i++) {
            int ci = t + 256 * i;
            int key = ci >> 5, c = ci & 31;
            *(uint4*)&Ks[key][c * 8] =
                *(const uint4*)(Kb + ((size_t)(b * 4096 + jb + key)) * 256 + c * 8);
            int d = ci >> 2, c2 = ci & 3;
            *(uint4*)&Vt[d][c2 * 8] =
                *(const uint4*)(Vtg + (size_t)b * 1048576 + (size_t)d * 4096 + jb + c2 * 8);
        }
        __syncthreads();

        // ---- S = Q K^T : 16 queries x 32 keys (2 key-tiles)
        f32x4 s0 = (f32x4)0.0f, s1 = (f32x4)0.0f;
#pragma unroll
        for (int ds = 0; ds < 8; ds++) {
            bf16x8 kf0 = *(const bf16x8*)&Ks[l15][ds * 32 + quad * 8];
            bf16x8 kf1 = *(const bf16x8*)&Ks[16 + l15][ds * 32 + quad * 8];
            s0 = __builtin_amdgcn_mfma_f32_16x16x32_bf16(qf[ds], kf0, s0, 0, 0, 0);
            s1 = __builtin_amdgcn_mfma_f32_16x16x32_bf16(qf[ds], kf1, s1, 0, 0, 0);
        }
        // ---- softcap + mask + exp (fixed max), P -> LDS
        const int j0 = jb + l15;
#pragma unroll
        for (int r = 0; r < 4; r++) {
            int qi = q0 + quad * 4 + r;
            float p0 = __expf(capmask(s0[r], qi, j0));
            float p1 = __expf(capmask(s1[r], qi, j0 + 16));
            u16 pb0 = f2b(p0), pb1 = f2b(p1);
            Pr[h][quad * 4 + r][l15]      = pb0;
            Pr[h][quad * 4 + r][16 + l15] = pb1;
            lp[r] += b2f(pb0) + b2f(pb1);
        }
        __threadfence_block();
        // ---- O^T += V^T P^T : 16 d-tiles, K=32 keys
#pragma unroll
        for (int mt = 0; mt < 16; mt++) {
            bf16x8 vf = *(const bf16x8*)&Vt[mt * 16 + l15][quad * 8];
            bf16x8 pf = *(const bf16x8*)&Pr[h][l15][quad * 8];
            o[mt] = __builtin_amdgcn_mfma_f32_16x16x32_bf16(vf, pf, o[mt], 0, 0, 0);
        }
    }

    // ---- l: reduce across the 16 key-lanes (q = quad*4 + r lives per quad)
#pragma unroll
    for (int r = 0; r < 4; r++) {
        float v = lp[r];
        v += __shfl_xor(v, 1, 64); v += __shfl_xor(v, 2, 64);
        v += __shfl_xor(v, 4, 64); v += __shfl_xor(v, 8, 64);
        lp[r] = v;
    }
    if (l15 == 0) {
#pragma unroll
        for (int r = 0; r < 4; r++) l_s[h][quad * 4 + r] = lp[r];
    }
    __threadfence_block();
    __syncthreads();
    const float inv = 1.0f / l_s[h][l15];

    // O^T C-layout: lane col = l15 = q; row = quad*4+reg = d within 16-tile
    u16* aop = AO + ((size_t)(b * 4096 + q0 + l15)) * 1024 + h * 256 + quad * 4;
#pragma unroll
    for (int mt = 0; mt < 16; mt++) {
        *(ushort4*)(aop + mt * 16) = make_ushort4(
            f2b(o[mt][0] * inv), f2b(o[mt][1] * inv),
            f2b(o[mt][2] * inv), f2b(o[mt][3] * inv));
    }
}

// ---------------------------------------------------------------------------
// K5: output projection (MFMA bf16 + global_load_lds staging).
// ---------------------------------------------------------------------------
__global__ __launch_bounds__(256) void out_gemm(
    const u16* __restrict__ AO, const u16* __restrict__ WoT,
    const void* __restrict__ cosT, void* __restrict__ outp)
{
    const bool isbf = detect_bf16(cosT);
    const int n0 = blockIdx.x * 128, m0 = blockIdx.y * 128;
    const int t = threadIdx.x, w = t >> 6, lane = t & 63;
    const int l15 = lane & 15, quad = lane >> 4;
    const int wm = (w & 1) * 64, wn = (w >> 1) * 64;

    __shared__ __align__(16) u16 Ah[128][32];
    __shared__ __align__(16) u16 Bh[128][32];

    f32x4 acc[4][4];
#pragma unroll
    for (int i = 0; i < 4; i++)
#pragma unroll
        for (int j = 0; j < 4; j++) acc[i][j] = (f32x4)0.0f;

    for (int kb = 0; kb < 1024; kb += 32) {
        __syncthreads();
#pragma unroll
        for (int i = 0; i < 2; i++) {
            int ci = t + 256 * i, m = ci >> 2, c = ci & 3;
            gll16(AO + (size_t)(m0 + m) * 1024 + kb + c * 8, (char*)&Ah[0][0] + ci * 16);
            gll16(WoT + (size_t)(n0 + m) * 1024 + kb + c * 8, (char*)&Bh[0][0] + ci * 16);
        }
        __syncthreads();
        bf16x8 af[4], bfr[4];
#pragma unroll
        for (int mi = 0; mi < 4; mi++)
            af[mi] = *(const bf16x8*)&Ah[wm + mi * 16 + l15][quad * 8];
#pragma unroll
        for (int ni = 0; ni < 4; ni++)
            bfr[ni] = *(const bf16x8*)&Bh[wn + ni * 16 + l15][quad * 8];
#pragma unroll
        for (int mi = 0; mi < 4; mi++)
#pragma unroll
            for (int ni = 0; ni < 4; ni++)
                acc[mi][ni] = __builtin_amdgcn_mfma_f32_16x16x32_bf16(
                    af[mi], bfr[ni], acc[mi][ni], 0, 0, 0);
    }

#pragma unroll
    for (int mi = 0; mi < 4; mi++)
#pragma unroll
        for (int ni = 0; ni < 4; ni++) {
            int rowb = m0 + wm + mi * 16 + quad * 4;
            int col  = n0 + wn + ni * 16 + l15;
            if (isbf) {
#pragma unroll
                for (int r = 0; r < 4; r++)
                    ((u16*)outp)[(size_t)(rowb + r) * 640 + col] = f2b(acc[mi][ni][r]);
            } else {
#pragma unroll
                for (int r = 0; r < 4; r++)
                    ((float*)outp)[(size_t)(rowb + r) * 640 + col] = acc[mi][ni][r];
            }
        }
}

// ---------------------------------------------------------------------------
// Launch. Inputs: 0 hidden, 1 cos, 2 sin, 3 mask(UNUSED), 4 Wq, 5 Wk, 6 Wv,
// 7 Wo, 8 q_norm_w, 9 k_norm_w. Workspace (43.3 MB, AO overlays Hb+WT):
//   [0, 16.78M): Hb(10.49M) + WT(1.97M)  -- dead after GEMMs; AO reuses @0
//   [16.78M): WoT 1.31M | Qb 16.78M | Kb 4.19M | Vt_g 4.19M
// ---------------------------------------------------------------------------
extern "C" void kernel_launch(void* const* d_in, const int* in_sizes, int n_in,
                              void* d_out, int out_size, void* d_ws, size_t ws_size,
                              hipStream_t stream) {
    const void* hidden = d_in[0];
    const void* cosT   = d_in[1];
    const void* sinT   = d_in[2];
    const void* Wq     = d_in[4];
    const void* Wk     = d_in[5];
    const void* Wv     = d_in[6];
    const void* Wo     = d_in[7];
    const void* qw     = d_in[8];
    const void* kw     = d_in[9];

    char* ws = (char*)d_ws;
    u16* Hb  = (u16*)ws;                            // 8192*640
    u16* WT  = (u16*)(ws + 10485760);               // 1536*640
    u16* AO  = (u16*)ws;                            // 8192*1024 (overlays Hb/WT)
    u16* WoT = (u16*)(ws + 16777216);               // 640*1024
    u16* Qb  = (u16*)(ws + 18087936);               // 8192*1024
    u16* Kb  = (u16*)(ws + 34865152);               // 8192*256
    u16* Vtg = (u16*)(ws + 39059456);               // 2*256*4096

    conv_hidden<<<dim3(2560), 256, 0, stream>>>(hidden, cosT, Hb);
    transpose_w<<<dim3(1600), 256, 0, stream>>>(Wq, Wk, Wv, Wo, cosT, WT, WoT);
    qkv_gemm<<<dim3(12, 64), 256, 0, stream>>>(Hb, WT, Qb, Kb, Vtg);
    norm_rope<<<dim3(8192), 320, 0, stream>>>(Qb, Kb, cosT, sinT, qw, kw);
    attn_mfma<<<dim3(256, 2), 256, 0, stream>>>(Qb, Kb, Vtg, AO);
    out_gemm<<<dim3(5, 64), 256, 0, stream>>>(AO, WoT, cosT, d_out);
}